// Round 13
// baseline (180.757 us; speedup 1.0000x reference)
//
#include <hip/hip_runtime.h>
#include <stdint.h>

// proj = einsum('bit,ih->tbh', x, W); scan: h=relu(p+0.8h(1-y)); y=thr(h+b,1).
// B=64, K=512, T=512, H=1024 fp32. Output: final y (64x1024).
//
// R18: KK=64, 8 phases, distributed staging, minimal drain. Six schedule
// variants (R7-R17) pin MfmaUtil at 41+-1% / ~950 TF. R17 lesson: the
// compiler already counts vmcnt for REGISTER loads (af) — only the
// global_load_lds DMA needs a manual wait (no reg dep). The untried m201
// parameter is BK=64: halves the per-kt serial boundaries (convert region,
// drain+barrier, addr recompute) and distributes staging so no phase is
// lumpy. Structure per kt (K=64, dbuf B 2x64KB, P aliases buf0):
//   p0-3: stage chunk p of B(kt+1)->buf^1 (2 DMA) + MFMA kk0 x ni-quad p
//   p4-7: loadA(kt+1) quarter (8 reg loads)     + MFMA kk1 x ni-quad
//   p4:   convert kk1 (compiler inserts its own counted vmcnt for af)
//   each phase: 8 ds_read b128 -> s_barrier -> setprio(1) 24 MFMA
//   setprio(0) -> [p7: vmcnt(32) — drains the 8 stage-DMAs, issued 4-7
//   phases (~4000cyc) earlier -> ~free; leaves all A loads flying] ->
//   s_barrier.
// Per-element accumulation order: kk0{hh,hl,lh} then kk1{...} ascending k
// == old kt,kt+1 sequence -> bit-identical; absmax must hold 0.03125.
// Geometry unchanged from R16/17: 8x1 waves (32t x 256h), A direct from
// global, W-only prepass (2MB ws), epilogue P[64][256]+swizzle, scan.

#define NB 64
#define NK 512
#define NT 512
#define NH 1024

#define TB 256     // t per block tile
#define HB 256     // h per block tile
#define KK 64      // k per step (2 x 32-slabs)
#define NKT (NK / KK)   // 8

typedef _Float16 h8_t __attribute__((ext_vector_type(8)));
typedef float    f4_t __attribute__((ext_vector_type(4)));

#define AS1 __attribute__((address_space(1)))
#define AS3 __attribute__((address_space(3)))

__device__ __forceinline__ void async_copy16(const void* g, void* l) {
    __builtin_amdgcn_global_load_lds((const AS1 uint32_t*)g, (AS3 uint32_t*)l, 16, 0, 0);
}

__device__ __forceinline__ void wait_all_barrier() {
    __builtin_amdgcn_s_waitcnt(0);   // vmcnt(0) expcnt(0) lgkmcnt(0)
    __syncthreads();
}

// ---- W-only pre-pass: fp32 [512][1024] -> fp16 hi/lo in fragment order
__global__ __launch_bounds__(256) void split_w(
    const float* __restrict__ Wm, _Float16* __restrict__ whi,
    _Float16* __restrict__ wlo)
{
    const int tid = threadIdx.x;
    const int cq  = tid & 15;     // col quad 0..15
    const int u   = tid >> 4;     // row octet 0..15

    const int bx = blockIdx.x;    // 0..15
    const int by = blockIdx.y;    // 0..3
    const int C  = NH;
    const int col0 = bx * 64;
    const int row0 = by * 128;
    const int ktbase = by * 4;

    const float* s = Wm + (size_t)(row0 + u * 8) * C + col0 + cq * 4;

    f4_t v[8];
    #pragma unroll
    for (int j = 0; j < 8; ++j)
        v[j] = *(const f4_t*)(s + (size_t)j * C);

    const int kt = ktbase + (u >> 2);
    const int ck = u & 3;

    #pragma unroll
    for (int i = 0; i < 4; ++i) {
        h8_t hi, lo;
        #pragma unroll
        for (int j = 0; j < 8; ++j) {
            float f = v[j][i] * 64.0f;       // 2^6 pre-scale
            _Float16 hh = (_Float16)f;
            hi[j] = hh;
            lo[j] = (_Float16)(f - (float)hh);
        }
        const int col = col0 + cq * 4 + i;
        const int ckp = ck ^ ((col >> 1) & 3);
        const size_t off = ((size_t)kt * C + col) * 32 + (size_t)ckp * 8;
        *(h8_t*)(whi + off) = hi;
        *(h8_t*)(wlo + off) = lo;
    }
}

// ---------------- main fused kernel (R18: KK=64, 8-phase) ---------------------
__global__ __launch_bounds__(512, 2) void fused_main(
    const float* __restrict__ X,
    const _Float16* __restrict__ whi, const _Float16* __restrict__ wlo,
    const float* __restrict__ bias, float* __restrict__ out)
{
    // [buf][kk-slab][hi/lo][8192] halfs = 131072 B total.
    __shared__ __align__(16) _Float16 SB[2][2][2][HB * 32];
    // Epilogue P[64][256] fp32 (64 KB) aliases buf0.
    float* Pf = (float*)&SB[0][0][0][0];

    const int tid  = threadIdx.x;
    const int lane = tid & 63;
    const int wid  = tid >> 6;     // 0..7 = t octant (32 rows each)
    const int l15  = lane & 15;
    const int lq   = lane >> 4;    // 0..3

    const int b  = blockIdx.x;
    const int h0 = blockIdx.y * HB;

    // B fragment LDS offset (halfs) within a kk-slab; swizzle matches prepass.
    const int sw   = (l15 >> 1) & 3;
    const int boff = (l15 * 4 + (lq ^ sw)) * 8;   // + ni*512, ni 0..15

    float hs = 0.0f, ys = 0.0f, bv = 0.0f;
    if (tid < HB) bv = bias[h0 + tid];

    const float INV_SCALE = 1.0f / 4096.0f;   // undo 2^6 x 2^6 operand scales

    // stage chunk c (0..3) of B(kt64) into buf: 2 DMA instrs / thread.
    auto stage_chunk = [&](int kt64, int buf, int c) {
        const int kt32 = kt64 * 2 + (c >> 1);
        const int ch   = tid + (c & 1) * 512;
        const _Float16* gb_hi = whi + ((size_t)kt32 * NH + h0) * 32;
        const _Float16* gb_lo = wlo + ((size_t)kt32 * NH + h0) * 32;
        async_copy16(gb_hi + ch * 8, &SB[buf][c >> 1][0][ch * 8]);
        async_copy16(gb_lo + ch * 8, &SB[buf][c >> 1][1][ch * 8]);
    };

    // A: af[kk][mi][j] = X[b][kt64*64 + kk*32 + lq*8 + j][tt0 + wid*32 + mi*16 + l15]
    float af[2][2][8];
    auto loadA_q = [&](int tt0_, int kt64, int kk, int mi) {   // 8 reg loads
        const float* g = X + ((size_t)(b * NK + kt64 * KK + kk * 32 + lq * 8)) * NT
                           + tt0_ + wid * 32 + l15;
        #pragma unroll
        for (int j = 0; j < 8; ++j)
            af[kk][mi][j] = g[(size_t)j * NT + mi * 16];
    };

    h8_t ah[2], al[2];
    auto convertA = [&](int kk) {
        #pragma unroll
        for (int mi = 0; mi < 2; ++mi)
            #pragma unroll
            for (int j = 0; j < 8; ++j) {
                float f = af[kk][mi][j] * 64.0f;   // bit-identical split
                _Float16 hh = (_Float16)f;
                ah[mi][j] = hh;
                al[mi][j] = (_Float16)(f - (float)hh);
            }
    };

    f4_t acc[2][16];

    // prologue: stage B(0)->buf0 FIRST (so boundary vmcnt(32) drains it),
    // then A(0) loads.
    #pragma unroll
    for (int c = 0; c < 4; ++c) stage_chunk(0, 0, c);
    loadA_q(0, 0, 0, 0); loadA_q(0, 0, 0, 1);
    loadA_q(0, 0, 1, 0); loadA_q(0, 0, 1, 1);

    for (int tt0 = 0; tt0 < NT; tt0 += TB) {
        #pragma unroll
        for (int mi = 0; mi < 2; ++mi)
            #pragma unroll
            for (int ni = 0; ni < 16; ++ni) {
                f4_t z = {0.f, 0.f, 0.f, 0.f};
                acc[mi][ni] = z;
            }

        // t-tile top boundary: drain the 8 stage-DMAs (oldest), leave the
        // 32 A reg-loads flying (compiler tracks them at convert).
        asm volatile("s_waitcnt vmcnt(32)" ::: "memory");
        __builtin_amdgcn_s_barrier();

        for (int kt = 0; kt < NKT; ++kt) {
            const int cur = kt & 1;
            const bool moreK = (kt + 1 < NKT);

            convertA(0);   // compiler inserts counted wait on af[0]

            #pragma unroll
            for (int p = 0; p < 8; ++p) {
                const int kk = p >> 2;        // 0 for p0-3, 1 for p4-7
                const int nibase = (p & 3) * 4;

                // ---- issue region (uniform across waves) ----
                if (p < 4) { if (moreK) stage_chunk(kt + 1, cur ^ 1, p); }
                else       { if (moreK) loadA_q(tt0, kt + 1, (p - 4) >> 1, (p - 4) & 1); }
                if (p == 4) convertA(1);      // compiler waits af[1]

                h8_t bh[4], bl[4];
                #pragma unroll
                for (int c = 0; c < 4; ++c) {
                    bh[c] = *(const h8_t*)(&SB[cur][kk][0][boff + (nibase + c) * 512]);
                    bl[c] = *(const h8_t*)(&SB[cur][kk][1][boff + (nibase + c) * 512]);
                }

                // ---- phase open ----
                __builtin_amdgcn_s_barrier();
                __builtin_amdgcn_s_setprio(1);
                #pragma unroll
                for (int c = 0; c < 4; ++c) {
                    const int ni = nibase + c;
                    // per-acc chain: hh -> hl -> lh (mode-outer / mi-inner)
                    #pragma unroll
                    for (int mi = 0; mi < 2; ++mi)
                        acc[mi][ni] = __builtin_amdgcn_mfma_f32_16x16x32_f16(ah[mi], bh[c], acc[mi][ni], 0, 0, 0);
                    #pragma unroll
                    for (int mi = 0; mi < 2; ++mi)
                        acc[mi][ni] = __builtin_amdgcn_mfma_f32_16x16x32_f16(ah[mi], bl[c], acc[mi][ni], 0, 0, 0);
                    #pragma unroll
                    for (int mi = 0; mi < 2; ++mi)
                        acc[mi][ni] = __builtin_amdgcn_mfma_f32_16x16x32_f16(al[mi], bh[c], acc[mi][ni], 0, 0, 0);
                }
                __builtin_amdgcn_s_setprio(0);
                // ---- phase close / kt boundary ----
                if (p == 7) {
                    // drain the 8 stage-DMAs (issued p0-3, ~4000cyc old);
                    // leave the 32 A loads flying.
                    asm volatile("s_waitcnt vmcnt(32)" ::: "memory");
                }
                __builtin_amdgcn_s_barrier();
            }
        }

        // epilogue boundary: full drain once per t-tile (queue ~empty)
        wait_all_barrier();

        // P[64][256] fp32 on buf0. Rows [sub*64, sub*64+64) from waves
        // wid = 2*sub, 2*sub+1. Swizzle col' = col ^ (((row>>2)&1)<<4);
        // writer key (lq&1) == reader key ((m>>2)&1).
        #pragma unroll 1
        for (int sub = 0; sub < 4; ++sub) {
            if ((wid >> 1) == sub) {
                #pragma unroll
                for (int mi = 0; mi < 2; ++mi)
                    #pragma unroll
                    for (int ni = 0; ni < 16; ++ni)
                        #pragma unroll
                        for (int r2 = 0; r2 < 4; ++r2) {
                            const int rloc = (wid & 1) * 32 + mi * 16 + lq * 4 + r2;
                            const int col  = (ni * 16 + l15) ^ ((lq & 1) << 4);
                            Pf[rloc * 256 + col] = acc[mi][ni][r2] * INV_SCALE;
                        }
            }
            __syncthreads();
            if (tid < HB) {
                const int cc2 = tid;   // h within block tile, 0..255
                #pragma unroll 8
                for (int m = 0; m < 64; ++m) {
                    float p = Pf[m * 256 + (cc2 ^ (((m >> 2) & 1) << 4))];
                    float pre = p + 0.8f * hs * (1.0f - ys);
                    hs = pre > 0.0f ? pre : 0.0f;
                    float z = hs + bv;
                    ys = (z > 1.0f) ? z : 0.0f;
                }
            }
            __syncthreads();   // scan done before next sub overwrites P
        }

        // next t-tile prologue (P dead; buf0 reusable). Stage FIRST, then
        // A loads, matching the boundary vmcnt(32) ledger.
        if (tt0 + TB < NT) {
            #pragma unroll
            for (int c = 0; c < 4; ++c) stage_chunk(0, 0, c);
            loadA_q(tt0 + TB, 0, 0, 0); loadA_q(tt0 + TB, 0, 0, 1);
            loadA_q(tt0 + TB, 0, 1, 0); loadA_q(tt0 + TB, 0, 1, 1);
        }
    }

    if (tid < HB)
        out[(size_t)b * NH + h0 + tid] = ys;
}

extern "C" void kernel_launch(void* const* d_in, const int* in_sizes, int n_in,
                              void* d_out, int out_size, void* d_ws, size_t ws_size,
                              hipStream_t stream) {
    const float* x    = (const float*)d_in[0];  // [64][512][512]
    const float* W    = (const float*)d_in[1];  // [512][1024]
    const float* bias = (const float*)d_in[2];  // [1024]
    float* out = (float*)d_out;

    _Float16* whi = (_Float16*)d_ws;            // 1 MB
    _Float16* wlo = whi + (size_t)NK * NH;      // 1 MB

    split_w<<<dim3(16, 4), 256, 0, stream>>>(W, whi, wlo);
    fused_main<<<dim3(NB, NH / HB), 512, 0, stream>>>(x, whi, wlo, bias, out);
}